// Round 13
// baseline (775.430 us; speedup 1.0000x reference)
//
#include <hip/hip_runtime.h>
#include <hip/hip_bf16.h>
#include <math.h>

typedef short bf16x8 __attribute__((ext_vector_type(8)));
typedef float f32x4 __attribute__((ext_vector_type(4)));
typedef unsigned int u32;
typedef unsigned short u16;

#define NROWS 131072
#define DDIM 224
#define HREAL 400
#define HP 416          // padded hidden dim (13*32)
#define ROWS 64         // rows per block
#define PROW 832        // bytes per plane row (416 * 2B = 52 units of 16B)
#define LDS_TOTAL 53248 // single bf16 activation plane [64][416]

// ---- workspace layout (bytes); weights interleaved hi|lo per fragment ----
#define OFF_W1    0          // [26nb][7ks][4g][16l][8hi|8lo] u16 = 372736 B
#define OFF_W2    372736     // [26][13][4][16][16] = 692224 B
#define OFF_W5    1064960    // 692224 B
#define OFF_W6    1757184    // [14][13][4][16][16] = 372736 B
#define OFF_C     2129920    // f32 scalar ||d||
#define OFF_MSEP  2129936    // f32 [4096]
#define OFF_DEFEN 2146320    // f32 [131072]
#define OFF_CAND  2670608    // f32 [1280]
#define OFF_WE3T  2675728    // f32 [4][416] transposed+padded We3
// total 2682384 bytes

__device__ __forceinline__ u16 f2bf(float v) {
  union { float f; u32 u; } a; a.f = v;
  u32 u = a.u;
  u += 0x7fffu + ((u >> 16) & 1u);   // round-to-nearest-even
  return (u16)(u >> 16);
}
__device__ __forceinline__ float bf2f(u16 h) {
  union { u32 u; float f; } a; a.u = ((u32)h) << 16; return a.f;
}
// rotation swizzle: 16B unit u of row r lives at unit (u+r) mod 52.
__device__ __forceinline__ int rotu(int r, int u) {
  int s = u + r;
  if (s >= 52) s -= 52;
  if (s >= 52) s -= 52;   // r<=63, u<=51 -> s<=114
  return s;
}

// interleaved fragment packing: u16 index i -> (nb, ks, g, l15, half, e)
__device__ __forceinline__ void pack16(int i, int NKS, int KREAL, int NREAL, int NLD,
                                       const float* __restrict__ W,
                                       u16* __restrict__ Wo) {
  const int e = i & 7, half = (i >> 3) & 1;
  const int l15 = (i >> 4) & 15, g = (i >> 8) & 3;
  const int rest = i >> 10;
  const int ks = rest % NKS, nb = rest / NKS;
  const int n = nb * 16 + l15, k = ks * 32 + g * 8 + e;
  const float w = (n < NREAL && k < KREAL) ? W[k * NLD + n] : 0.f;
  const u16 h = f2bf(w);
  Wo[i] = half ? f2bf(w - bf2f(h)) : h;
}

__global__ void k_prep(const float* __restrict__ We1, const float* __restrict__ We2,
                       const float* __restrict__ Wd2, const float* __restrict__ Wd3,
                       const float* __restrict__ We3, const float* __restrict__ dvec,
                       u16* __restrict__ W1, u16* __restrict__ W2,
                       u16* __restrict__ W5, u16* __restrict__ W6,
                       float* __restrict__ We3T, float* __restrict__ Cout) {
  const int t = blockIdx.x * 256 + threadIdx.x;
  const int NT = gridDim.x * 256;
  for (int i = t; i < 26 * 7 * 1024;  i += NT) pack16(i, 7,  DDIM,  HREAL, HREAL, We1, W1);
  for (int i = t; i < 26 * 13 * 1024; i += NT) pack16(i, 13, HREAL, HREAL, HREAL, We2, W2);
  for (int i = t; i < 26 * 13 * 1024; i += NT) pack16(i, 13, HREAL, HREAL, HREAL, Wd2, W5);
  for (int i = t; i < 14 * 13 * 1024; i += NT) pack16(i, 13, HREAL, DDIM,  DDIM,  Wd3, W6);
  for (int i = t; i < 4 * 416; i += NT) {      // We3T[j][k] = We3[k][j], zero-padded
    const int j = i / 416, k = i - j * 416;
    We3T[i] = (k < HREAL) ? We3[k * 4 + j] : 0.f;
  }
  if (blockIdx.x == 0) {
    float s = 0.f;
    for (int i = threadIdx.x; i < DDIM; i += 256) { float v = dvec[i]; s += v * v; }
#pragma unroll
    for (int off = 1; off < 64; off <<= 1) s += __shfl_xor(s, off);
    __shared__ float cs[4];
    if ((threadIdx.x & 63) == 0) cs[threadIdx.x >> 6] = s;
    __syncthreads();
    if (threadIdx.x == 0) Cout[0] = sqrtf(cs[0] + cs[1] + cs[2] + cs[3]);
  }
}

// ---------------- GEMM core: one wave, 4 M-frags x NFW N-frags ----------------
// A bf16 from LDS (64 rows); W split hi+lo (2 MFMAs per tile). 16 MFMAs per
// 32B-of-weights at NFW>=1 — 2x the arithmetic intensity of the 2-M-frag core.
template <int NKS, int NFW>
__device__ __forceinline__ void gemm_acc(const char* hp,
    const u16* __restrict__ W, int nb0, int l15, int g, f32x4 (&acc)[4][4]) {
  const int lof = (g << 8) + (l15 << 4);
#pragma unroll 2
  for (int ks = 0; ks < NKS; ++ks) {
    bf16x8 a[4];
#pragma unroll
    for (int mf = 0; mf < 4; ++mf) {
      const int row = mf * 16 + l15;
      int s = ks * 4 + g + row;
      if (s >= 52) s -= 52;
      if (s >= 52) s -= 52;
      a[mf] = *(const bf16x8*)(hp + row * PROW + s * 16);
    }
#pragma unroll
    for (int nf = 0; nf < NFW; ++nf) {
      const u16* base = W + ((((size_t)(nb0 + nf) * NKS + ks) << 10) + lof);
      const bf16x8 bh = *(const bf16x8*)base;
      const bf16x8 bl = *(const bf16x8*)(base + 8);
      __builtin_amdgcn_s_setprio(1);
#pragma unroll
      for (int mf = 0; mf < 4; ++mf) {
        acc[mf][nf] = __builtin_amdgcn_mfma_f32_16x16x32_bf16(a[mf], bh, acc[mf][nf], 0, 0, 0);
        acc[mf][nf] = __builtin_amdgcn_mfma_f32_16x16x32_bf16(a[mf], bl, acc[mf][nf], 0, 0, 0);
      }
      __builtin_amdgcn_s_setprio(0);
    }
  }
}

// ---------------- activation epilogue: bias + lrelu -> plane ----------------
template <int NFW>
__device__ __forceinline__ void epi_act(f32x4 (&acc)[4][4], const float* __restrict__ bias,
                                        int nb0, char* hp, int l15, int g) {
#pragma unroll
  for (int nf = 0; nf < NFW; ++nf) {
    const int col = (nb0 + nf) * 16 + l15;
    const float bv = (col < HREAL) ? bias[col] : 0.f;
    const int cu = col >> 3;            // 16B unit index
    const int crem = (col & 7) * 2;     // byte within unit
#pragma unroll
    for (int mf = 0; mf < 4; ++mf) {
#pragma unroll
      for (int j = 0; j < 4; ++j) {
        const int row = mf * 16 + g * 4 + j;
        float v = acc[mf][nf][j] + bv;
        v = fmaxf(v, 0.1f * v);
        *(u16*)(hp + row * PROW + rotu(row, cu) * 16 + crem) = f2bf(v);
      }
    }
  }
}

// ---------------- main fused kernel: 64 rows per block, 512 threads ----------------
__global__ __launch_bounds__(512, 2) void k_main(
    const float* __restrict__ xin, const float* __restrict__ dvec,
    const float* __restrict__ be1, const float* __restrict__ be2, const float* __restrict__ be3,
    const float* __restrict__ bd1, const float* __restrict__ bd2, const float* __restrict__ bd3,
    const float* __restrict__ We3T, const float* __restrict__ Wd1,
    const u16* __restrict__ W1, const u16* __restrict__ W2,
    const u16* __restrict__ W5, const u16* __restrict__ W6,
    const float* __restrict__ Cptr,
    float* __restrict__ y_out, float* __restrict__ z_out,
    float* __restrict__ defen, float* __restrict__ msep) {
  extern __shared__ __align__(16) char lds[];
  char* hp = lds;              // [64][416] bf16 activation plane, rotation-swizzled

  const int tid = threadIdx.x;
  const int lane = tid & 63;
  const int wid = tid >> 6;       // 0..7
  const int l15 = lane & 15;
  const int g = lane >> 4;        // 0..3
  const int row0 = blockIdx.x * ROWS;
  // hidden layers: 26 n-blocks over 8 waves -> {4,4,3,3,3,3,3,3}
  const int nb0_26 = (wid < 2) ? wid * 4 : 8 + (wid - 2) * 3;

  // ---- stage x -> plane (bf16) ----
#pragma unroll
  for (int i = 0; i < 7; ++i) {
    const int f = i * 512 + tid;                 // 64 rows * 56 float4 = 3584
    const int r = f / 56, c4 = f - r * 56;
    const float4 v = *(const float4*)(xin + (size_t)(row0 + r) * DDIM + c4 * 4);
    const float vv[4] = {v.x, v.y, v.z, v.w};
    ushort4 hh;
    u16* hw = (u16*)&hh;
#pragma unroll
    for (int w = 0; w < 4; ++w) hw[w] = f2bf(vv[w]);
    *(ushort4*)(hp + r * PROW + rotu(r, c4 >> 1) * 16 + (c4 & 1) * 8) = hh;
  }
  __syncthreads();

  // ---- L1: x(224) -> h1 ----
  {
    f32x4 acc[4][4] = {};
    if (wid < 2) gemm_acc<7, 4>(hp, W1, nb0_26, l15, g, acc);
    else         gemm_acc<7, 3>(hp, W1, nb0_26, l15, g, acc);
    __syncthreads();
    if (wid < 2) epi_act<4>(acc, be1, nb0_26, hp, l15, g);
    else         epi_act<3>(acc, be1, nb0_26, hp, l15, g);
  }
  __syncthreads();

  // ---- L2: h1 -> h2 ----
  {
    f32x4 acc[4][4] = {};
    if (wid < 2) gemm_acc<13, 4>(hp, W2, nb0_26, l15, g, acc);
    else         gemm_acc<13, 3>(hp, W2, nb0_26, l15, g, acc);
    __syncthreads();
    if (wid < 2) epi_act<4>(acc, be2, nb0_26, hp, l15, g);
    else         epi_act<3>(acc, be2, nb0_26, hp, l15, g);
  }
  __syncthreads();

  // ---- L3: z = h2 @ We3 + be3 (Z=4), f32; 8 threads/row (j x K-half) ----
  float zval;   // finished z_{t8&3} for row tid>>3 (all 8 lanes after reduce)
  {
    const int r = tid >> 3;          // 0..63
    const int t8 = tid & 7;
    const int j = t8 & 3, half = t8 >> 2;
    const char* hb = hp + r * PROW;
    const float* wrow = We3T + j * 416;
    float s0 = 0.f, s1 = 0.f;
#pragma unroll 2
    for (int it = 0; it < 25; ++it) {
      const int k = half * 200 + it * 8;
      const bf16x8 h8 = *(const bf16x8*)(hb + rotu(r, half * 25 + it) * 16);
      const float4 w0 = *(const float4*)(wrow + k);
      const float4 w1 = *(const float4*)(wrow + k + 4);
      s0 = fmaf(bf2f((u16)h8[0]), w0.x, s0);
      s1 = fmaf(bf2f((u16)h8[1]), w0.y, s1);
      s0 = fmaf(bf2f((u16)h8[2]), w0.z, s0);
      s1 = fmaf(bf2f((u16)h8[3]), w0.w, s1);
      s0 = fmaf(bf2f((u16)h8[4]), w1.x, s0);
      s1 = fmaf(bf2f((u16)h8[5]), w1.y, s1);
      s0 = fmaf(bf2f((u16)h8[6]), w1.z, s0);
      s1 = fmaf(bf2f((u16)h8[7]), w1.w, s1);
    }
    float s = s0 + s1;
    s += __shfl_xor(s, 4);           // combine K-halves, preserve j
    s += be3[j];
    zval = s;
    if (half == 0) z_out[(size_t)(row0 + r) * 4 + j] = s;
  }
  // no barrier: row r is read (L3) and written (L4) only by its own 8-thread
  // group inside one wave; program order serializes them.

  // ---- L4: g1 = lrelu(z @ Wd1 + bd1) -> plane ----
  {
    const int r = tid >> 3, q = tid & 7;
    float z[4];
#pragma unroll
    for (int jj = 0; jj < 4; ++jj) z[jj] = __shfl(zval, (lane & ~7) + jj);
#pragma unroll 2
    for (int u = 0; u < 13; ++u) {
      const int c4 = q * 13 + u;                 // 104 groups of 4 cols = 416
      ushort4 hh;
      u16* hw = (u16*)&hh;
      if (c4 < 100) {                            // cols < 400
        const float4 w0 = *(const float4*)(Wd1 + 0 * HREAL + c4 * 4);
        const float4 w1 = *(const float4*)(Wd1 + 1 * HREAL + c4 * 4);
        const float4 w2 = *(const float4*)(Wd1 + 2 * HREAL + c4 * 4);
        const float4 w3 = *(const float4*)(Wd1 + 3 * HREAL + c4 * 4);
        const float4 bb = *(const float4*)(bd1 + c4 * 4);
        const float ww[4][4] = {{w0.x, w1.x, w2.x, w3.x}, {w0.y, w1.y, w2.y, w3.y},
                                {w0.z, w1.z, w2.z, w3.z}, {w0.w, w1.w, w2.w, w3.w}};
        const float bbv[4] = {bb.x, bb.y, bb.z, bb.w};
#pragma unroll
        for (int w = 0; w < 4; ++w) {
          float v = fmaf(z[0], ww[w][0], fmaf(z[1], ww[w][1],
                    fmaf(z[2], ww[w][2], fmaf(z[3], ww[w][3], bbv[w]))));
          v = fmaxf(v, 0.1f * v);
          hw[w] = f2bf(v);
        }
      } else {
        hw[0] = hw[1] = hw[2] = hw[3] = 0;
      }
      *(ushort4*)(hp + r * PROW + rotu(r, c4 >> 1) * 16 + (c4 & 1) * 8) = hh;
    }
  }
  __syncthreads();

  // ---- L5: g2 = lrelu(g1 @ Wd2 + bd2) ----
  {
    f32x4 acc[4][4] = {};
    if (wid < 2) gemm_acc<13, 4>(hp, W5, nb0_26, l15, g, acc);
    else         gemm_acc<13, 3>(hp, W5, nb0_26, l15, g, acc);
    __syncthreads();
    if (wid < 2) epi_act<4>(acc, bd2, nb0_26, hp, l15, g);
    else         epi_act<3>(acc, bd2, nb0_26, hp, l15, g);
  }
  __syncthreads();

  // ---- L6: y = tanh(g2 @ Wd3 + bd3) + fused reductions ----
  // 14 n-blocks over 8 waves -> {2,2,2,2,2,2,1,1}
  {
    const int nb0 = (wid < 6) ? wid * 2 : 12 + (wid - 6);
    const int nfw = (wid < 6) ? 2 : 1;
    f32x4 acc[4][4] = {};
    if (wid < 6) gemm_acc<13, 2>(hp, W6, nb0, l15, g, acc);
    else         gemm_acc<13, 1>(hp, W6, nb0, l15, g, acc);
    __syncthreads();               // all plane reads done; red overlays plane
    float* red = (float*)lds;      // [64 rows][8 waves][4]
#pragma unroll
    for (int mf = 0; mf < 4; ++mf) {
#pragma unroll
      for (int j = 0; j < 4; ++j) {
        const int lrow = mf * 16 + g * 4 + j;
        const int grow = row0 + lrow;
        float pA = 0.f, pB = 0.f, pM = 0.f;
#pragma unroll
        for (int nf = 0; nf < 2; ++nf) {
          if (nf < nfw) {
            const int col = (nb0 + nf) * 16 + l15;
            const float v = acc[mf][nf][j] + bd3[col];
            const float e = __expf(2.f * v);
            const float y = 1.f - 2.f * __builtin_amdgcn_rcpf(e + 1.f);
            y_out[(size_t)grow * DDIM + col] = y;
            pA = fmaf(y, dvec[col], pA);
            pB = fmaf(y, y, pB);
            const float df = y - xin[(size_t)grow * DDIM + col];
            pM = fmaf(df, df, pM);
          }
        }
#pragma unroll
        for (int off = 1; off < 16; off <<= 1) {
          pA += __shfl_xor(pA, off);
          pB += __shfl_xor(pB, off);
          pM += __shfl_xor(pM, off);
        }
        if (l15 == 0) {
          red[(lrow * 8 + wid) * 4 + 0] = pA;
          red[(lrow * 8 + wid) * 4 + 1] = pB;
          red[(lrow * 8 + wid) * 4 + 2] = pM;
        }
      }
    }
  }
  __syncthreads();

  if (tid < 64) {
    const float Cn = Cptr[0];
    const float* red = (const float*)lds;
    float A = 0.f, B2 = 0.f, M = 0.f;
#pragma unroll
    for (int w = 0; w < 8; ++w) {
      A  += red[(tid * 8 + w) * 4 + 0];
      B2 += red[(tid * 8 + w) * 4 + 1];
      M  += red[(tid * 8 + w) * 4 + 2];
    }
    defen[row0 + tid] = A / (sqrtf(B2) * Cn + 1e-5f);
#pragma unroll
    for (int off = 1; off < 64; off <<= 1) M += __shfl_xor(M, off);
    if (tid == 0) msep[blockIdx.x] = M;
  }
}

// ---------------- top-k stage A: 64 blocks, per-block top-20 of 2048 ----------------
__global__ void k_topk_a(const float* __restrict__ defen, float* __restrict__ cand) {
  __shared__ float vals[2048];
  __shared__ float wv[4];
  __shared__ int wi[4];
  const int tid = threadIdx.x;
  const int base = blockIdx.x * 2048;
  for (int i = tid; i < 2048; i += 256) vals[i] = defen[base + i];
  __syncthreads();
  for (int it = 0; it < 20; ++it) {
    float mv = -1e30f; int mi = 1 << 30;
    for (int i = tid; i < 2048; i += 256) {
      float v = vals[i];
      if (v > mv) { mv = v; mi = i; }
    }
#pragma unroll
    for (int off = 1; off < 64; off <<= 1) {
      float ov = __shfl_xor(mv, off); int oi = __shfl_xor(mi, off);
      if (ov > mv || (ov == mv && oi < mi)) { mv = ov; mi = oi; }
    }
    if ((tid & 63) == 0) { wv[tid >> 6] = mv; wi[tid >> 6] = mi; }
    __syncthreads();
    if (tid == 0) {
      float bv = wv[0]; int bi = wi[0];
      for (int q = 1; q < 4; ++q)
        if (wv[q] > bv || (wv[q] == bv && wi[q] < bi)) { bv = wv[q]; bi = wi[q]; }
      cand[blockIdx.x * 20 + it] = bv;
      vals[bi] = -1e30f;
    }
    __syncthreads();
  }
}

// ---------------- top-k stage B: final top-20 of 1280 + R_loss ----------------
__global__ void k_topk_b(const float* __restrict__ cand, const float* __restrict__ msep,
                         float* __restrict__ rloss) {
  __shared__ float vals[1280];
  __shared__ float wv[4];
  __shared__ int wi[4];
  __shared__ float msum[4];
  const int tid = threadIdx.x;
  for (int i = tid; i < 1280; i += 256) vals[i] = cand[i];
  float ms = 0.f;
  for (int i = tid; i < 2048; i += 256) ms += msep[i];
#pragma unroll
  for (int off = 1; off < 64; off <<= 1) ms += __shfl_xor(ms, off);
  if ((tid & 63) == 0) msum[tid >> 6] = ms;
  __syncthreads();
  float sam = 0.f;
  for (int it = 0; it < 20; ++it) {
    float mv = -1e30f; int mi = 1 << 30;
    for (int i = tid; i < 1280; i += 256) {
      float v = vals[i];
      if (v > mv) { mv = v; mi = i; }
    }
#pragma unroll
    for (int off = 1; off < 64; off <<= 1) {
      float ov = __shfl_xor(mv, off); int oi = __shfl_xor(mi, off);
      if (ov > mv || (ov == mv && oi < mi)) { mv = ov; mi = oi; }
    }
    if ((tid & 63) == 0) { wv[tid >> 6] = mv; wi[tid >> 6] = mi; }
    __syncthreads();
    if (tid == 0) {
      float bv = wv[0]; int bi = wi[0];
      for (int q = 1; q < 4; ++q)
        if (wv[q] > bv || (wv[q] == bv && wi[q] < bi)) { bv = wv[q]; bi = wi[q]; }
      sam += bv;
      vals[bi] = -1e30f;
    }
    __syncthreads();
  }
  if (tid == 0) {
    float mse = (msum[0] + msum[1] + msum[2] + msum[3]) / 29360128.f;  // N*D
    rloss[0] = mse + 0.1f * sam;
  }
}

extern "C" void kernel_launch(void* const* d_in, const int* in_sizes, int n_in,
                              void* d_out, int out_size, void* d_ws, size_t ws_size,
                              hipStream_t stream) {
  const float* x    = (const float*)d_in[0];
  const float* dinp = (const float*)d_in[1];
  const float* We1  = (const float*)d_in[2];
  const float* be1  = (const float*)d_in[3];
  const float* We2  = (const float*)d_in[4];
  const float* be2  = (const float*)d_in[5];
  const float* We3  = (const float*)d_in[6];
  const float* be3  = (const float*)d_in[7];
  const float* Wd1  = (const float*)d_in[8];
  const float* bd1  = (const float*)d_in[9];
  const float* Wd2  = (const float*)d_in[10];
  const float* bd2  = (const float*)d_in[11];
  const float* Wd3  = (const float*)d_in[12];
  const float* bd3  = (const float*)d_in[13];

  float* y_out = (float*)d_out;
  float* z_out = y_out + (size_t)NROWS * DDIM;
  float* r_out = z_out + (size_t)NROWS * 4;

  char* ws = (char*)d_ws;
  u16* W1 = (u16*)(ws + OFF_W1);
  u16* W2 = (u16*)(ws + OFF_W2);
  u16* W5 = (u16*)(ws + OFF_W5);
  u16* W6 = (u16*)(ws + OFF_W6);
  float* Cf    = (float*)(ws + OFF_C);
  float* msep  = (float*)(ws + OFF_MSEP);
  float* defen = (float*)(ws + OFF_DEFEN);
  float* cand  = (float*)(ws + OFF_CAND);
  float* We3T  = (float*)(ws + OFF_WE3T);

  (void)hipFuncSetAttribute((const void*)k_main, hipFuncAttributeMaxDynamicSharedMemorySize, LDS_TOTAL);

  k_prep<<<dim3(256), dim3(256), 0, stream>>>(We1, We2, Wd2, Wd3, We3, dinp,
                                              W1, W2, W5, W6, We3T, Cf);
  k_main<<<dim3(2048), dim3(512), LDS_TOTAL, stream>>>(x, dinp, be1, be2, be3, bd1, bd2, bd3,
                                                       We3T, Wd1, W1, W2, W5, W6,
                                                       Cf, y_out, z_out, defen, msep);
  k_topk_a<<<dim3(64), dim3(256), 0, stream>>>(defen, cand);
  k_topk_b<<<dim3(1), dim3(256), 0, stream>>>(cand, msep, r_out);
}

// Round 14
// 497.178 us; speedup vs baseline: 1.5597x; 1.5597x over previous
//
#include <hip/hip_runtime.h>
#include <hip/hip_bf16.h>
#include <math.h>

typedef short bf16x8 __attribute__((ext_vector_type(8)));
typedef float f32x4 __attribute__((ext_vector_type(4)));
typedef unsigned int u32;
typedef unsigned short u16;

#define NROWS 131072
#define DDIM 224
#define HREAL 400
#define HP 416          // padded hidden dim (13*32)
#define ROWS 32         // rows per block
#define PROW 832        // bytes per plane row (416 * 2B = 52 units of 16B)
#define PLANE 26624     // one plane: [32][416] bf16
#define LDS_TOTAL 53248 // plane A + plane B (ping-pong); 3 blocks/CU

// ---- workspace layout (bytes); weights interleaved hi|lo per fragment ----
#define OFF_W1    0          // [26nb][7ks][4g][16l][8hi|8lo] u16 = 372736 B
#define OFF_W2    372736     // [26][13][4][16][16] = 692224 B
#define OFF_W5    1064960    // 692224 B
#define OFF_W6    1757184    // [14][13][4][16][16] = 372736 B
#define OFF_C     2129920    // f32 scalar ||d||
#define OFF_MSEP  2129936    // f32 [4096]
#define OFF_DEFEN 2146320    // f32 [131072]
#define OFF_CAND  2670608    // f32 [1280]
#define OFF_WE3T  2675728    // f32 [4][416] transposed+padded We3
// total 2682384 bytes

__device__ __forceinline__ u16 f2bf(float v) {
  union { float f; u32 u; } a; a.f = v;
  u32 u = a.u;
  u += 0x7fffu + ((u >> 16) & 1u);   // round-to-nearest-even
  return (u16)(u >> 16);
}
__device__ __forceinline__ float bf2f(u16 h) {
  union { u32 u; float f; } a; a.u = ((u32)h) << 16; return a.f;
}
// rotation swizzle: 16B unit u of row r lives at unit (u+r) mod 52.
__device__ __forceinline__ int rotu(int r, int u) {
  int s = u + r;
  if (s >= 52) s -= 52;
  if (s >= 52) s -= 52;
  return s;
}

// interleaved fragment packing: u16 index i -> (nb, ks, g, l15, half, e)
__device__ __forceinline__ void pack16(int i, int NKS, int KREAL, int NREAL, int NLD,
                                       const float* __restrict__ W,
                                       u16* __restrict__ Wo) {
  const int e = i & 7, half = (i >> 3) & 1;
  const int l15 = (i >> 4) & 15, g = (i >> 8) & 3;
  const int rest = i >> 10;
  const int ks = rest % NKS, nb = rest / NKS;
  const int n = nb * 16 + l15, k = ks * 32 + g * 8 + e;
  const float w = (n < NREAL && k < KREAL) ? W[k * NLD + n] : 0.f;
  const u16 h = f2bf(w);
  Wo[i] = half ? f2bf(w - bf2f(h)) : h;
}

__global__ void k_prep(const float* __restrict__ We1, const float* __restrict__ We2,
                       const float* __restrict__ Wd2, const float* __restrict__ Wd3,
                       const float* __restrict__ We3, const float* __restrict__ dvec,
                       u16* __restrict__ W1, u16* __restrict__ W2,
                       u16* __restrict__ W5, u16* __restrict__ W6,
                       float* __restrict__ We3T, float* __restrict__ Cout) {
  const int t = blockIdx.x * 256 + threadIdx.x;
  const int NT = gridDim.x * 256;
  for (int i = t; i < 26 * 7 * 1024;  i += NT) pack16(i, 7,  DDIM,  HREAL, HREAL, We1, W1);
  for (int i = t; i < 26 * 13 * 1024; i += NT) pack16(i, 13, HREAL, HREAL, HREAL, We2, W2);
  for (int i = t; i < 26 * 13 * 1024; i += NT) pack16(i, 13, HREAL, HREAL, HREAL, Wd2, W5);
  for (int i = t; i < 14 * 13 * 1024; i += NT) pack16(i, 13, HREAL, DDIM,  DDIM,  Wd3, W6);
  for (int i = t; i < 4 * 416; i += NT) {      // We3T[j][k] = We3[k][j], zero-padded
    const int j = i / 416, k = i - j * 416;
    We3T[i] = (k < HREAL) ? We3[k * 4 + j] : 0.f;
  }
  if (blockIdx.x == 0) {
    float s = 0.f;
    for (int i = threadIdx.x; i < DDIM; i += 256) { float v = dvec[i]; s += v * v; }
#pragma unroll
    for (int off = 1; off < 64; off <<= 1) s += __shfl_xor(s, off);
    __shared__ float cs[4];
    if ((threadIdx.x & 63) == 0) cs[threadIdx.x >> 6] = s;
    __syncthreads();
    if (threadIdx.x == 0) Cout[0] = sqrtf(cs[0] + cs[1] + cs[2] + cs[3]);
  }
}

// ------- GEMM chunk: 2 M-frags x 2 N-frags, 1-k-step-deep weight prefetch -------
// Small live set (acc=16, cw=16, nw=16 transient) so several chunks + prefetch
// fit the register budget without spill.
template <int NKS>
__device__ __forceinline__ void gemm2(const char* ip, const u16* __restrict__ W,
                                      int nb0, int l15, int g, f32x4 (&acc)[2][2]) {
  const int lof = (g << 8) + (l15 << 4);
  const u16* w0 = W + ((((size_t)nb0 * NKS) << 10) + lof);
  const u16* w1 = W + ((((size_t)(nb0 + 1) * NKS) << 10) + lof);
  bf16x8 c0h = *(const bf16x8*)w0;
  bf16x8 c0l = *(const bf16x8*)(w0 + 8);
  bf16x8 c1h = *(const bf16x8*)w1;
  bf16x8 c1l = *(const bf16x8*)(w1 + 8);
#pragma unroll
  for (int ks = 0; ks < NKS; ++ks) {
    int s0 = ks * 4 + g + l15;
    if (s0 >= 52) s0 -= 52;
    int s1 = s0 + 16;
    if (s1 >= 52) s1 -= 52;
    const bf16x8 a0 = *(const bf16x8*)(ip + l15 * PROW + s0 * 16);
    const bf16x8 a1 = *(const bf16x8*)(ip + (l15 + 16) * PROW + s1 * 16);
    bf16x8 n0h, n0l, n1h, n1l;
    if (ks + 1 < NKS) {
      const u16* p0 = w0 + (size_t)(ks + 1) * 1024;
      const u16* p1 = w1 + (size_t)(ks + 1) * 1024;
      n0h = *(const bf16x8*)p0;
      n0l = *(const bf16x8*)(p0 + 8);
      n1h = *(const bf16x8*)p1;
      n1l = *(const bf16x8*)(p1 + 8);
    }
    __builtin_amdgcn_s_setprio(1);
    acc[0][0] = __builtin_amdgcn_mfma_f32_16x16x32_bf16(a0, c0h, acc[0][0], 0, 0, 0);
    acc[0][0] = __builtin_amdgcn_mfma_f32_16x16x32_bf16(a0, c0l, acc[0][0], 0, 0, 0);
    acc[1][0] = __builtin_amdgcn_mfma_f32_16x16x32_bf16(a1, c0h, acc[1][0], 0, 0, 0);
    acc[1][0] = __builtin_amdgcn_mfma_f32_16x16x32_bf16(a1, c0l, acc[1][0], 0, 0, 0);
    acc[0][1] = __builtin_amdgcn_mfma_f32_16x16x32_bf16(a0, c1h, acc[0][1], 0, 0, 0);
    acc[0][1] = __builtin_amdgcn_mfma_f32_16x16x32_bf16(a0, c1l, acc[0][1], 0, 0, 0);
    acc[1][1] = __builtin_amdgcn_mfma_f32_16x16x32_bf16(a1, c1h, acc[1][1], 0, 0, 0);
    acc[1][1] = __builtin_amdgcn_mfma_f32_16x16x32_bf16(a1, c1l, acc[1][1], 0, 0, 0);
    __builtin_amdgcn_s_setprio(0);
    if (ks + 1 < NKS) { c0h = n0h; c0l = n0l; c1h = n1h; c1l = n1l; }
  }
}

// ---------------- activation epilogue: bias + lrelu -> OUT plane ----------------
__device__ __forceinline__ void epi2(f32x4 (&acc)[2][2], const float* __restrict__ bias,
                                     int nb0, char* op, int l15, int g) {
#pragma unroll
  for (int nf = 0; nf < 2; ++nf) {
    const int col = (nb0 + nf) * 16 + l15;
    const float bv = (col < HREAL) ? bias[col] : 0.f;
    const int cu = col >> 3;
    const int crem = (col & 7) * 2;
#pragma unroll
    for (int mf = 0; mf < 2; ++mf) {
#pragma unroll
      for (int j = 0; j < 4; ++j) {
        const int row = mf * 16 + g * 4 + j;
        float v = acc[mf][nf][j] + bv;
        v = fmaxf(v, 0.1f * v);
        *(u16*)(op + row * PROW + rotu(row, cu) * 16 + crem) = f2bf(v);
      }
    }
  }
}

// ---------------- main fused kernel: 32 rows per block, 256 threads ----------------
// Ping-pong planes: each layer reads one plane, writes the other -> 1 barrier/layer.
__global__ __launch_bounds__(256, 3) void k_main(
    const float* __restrict__ xin, const float* __restrict__ dvec,
    const float* __restrict__ be1, const float* __restrict__ be2, const float* __restrict__ be3,
    const float* __restrict__ bd1, const float* __restrict__ bd2, const float* __restrict__ bd3,
    const float* __restrict__ We3T, const float* __restrict__ Wd1,
    const u16* __restrict__ W1, const u16* __restrict__ W2,
    const u16* __restrict__ W5, const u16* __restrict__ W6,
    const float* __restrict__ Cptr,
    float* __restrict__ y_out, float* __restrict__ z_out,
    float* __restrict__ defen, float* __restrict__ msep) {
  extern __shared__ __align__(16) char lds[];
  char* pa = lds;              // plane A
  char* pb = lds + PLANE;      // plane B

  const int tid = threadIdx.x;
  const int lane = tid & 63;
  const int wid = tid >> 6;       // 0..3
  const int l15 = lane & 15;
  const int g = lane >> 4;        // 0..3
  const int row0 = blockIdx.x * ROWS;

  // ---- stage x -> plane A ----
#pragma unroll
  for (int i = 0; i < 7; ++i) {
    const int f = i * 256 + tid;                 // 32 rows * 56 float4 = 1792
    const int r = f / 56, c4 = f - r * 56;
    const float4 v = *(const float4*)(xin + (size_t)(row0 + r) * DDIM + c4 * 4);
    const float vv[4] = {v.x, v.y, v.z, v.w};
    ushort4 hh;
    u16* hw = (u16*)&hh;
#pragma unroll
    for (int w = 0; w < 4; ++w) hw[w] = f2bf(vv[w]);
    *(ushort4*)(pa + r * PROW + rotu(r, c4 >> 1) * 16 + (c4 & 1) * 8) = hh;
  }
  __syncthreads();

  // ---- L1: x(A) -> h1(B); 13 chunks of 2 nb round-robin over 4 waves ----
  for (int c = wid; c < 13; c += 4) {
    f32x4 acc[2][2] = {};
    gemm2<7>(pa, W1, 2 * c, l15, g, acc);
    epi2(acc, be1, 2 * c, pb, l15, g);
  }
  __syncthreads();

  // ---- L2: h1(B) -> h2(A) ----
  for (int c = wid; c < 13; c += 4) {
    f32x4 acc[2][2] = {};
    gemm2<13>(pb, W2, 2 * c, l15, g, acc);
    epi2(acc, be2, 2 * c, pa, l15, g);
  }
  __syncthreads();

  // ---- L3: z = h2(A) @ We3 + be3 (Z=4), f32; 8 threads/row ----
  float zval;
  {
    const int r = tid >> 3;          // 0..31
    const int t8 = tid & 7;
    const int j = t8 & 3, half = t8 >> 2;
    const char* hb = pa + r * PROW;
    const float* wrow = We3T + j * 416;
    float s0 = 0.f, s1 = 0.f;
#pragma unroll 2
    for (int it = 0; it < 25; ++it) {
      const int k = half * 200 + it * 8;
      const bf16x8 h8 = *(const bf16x8*)(hb + rotu(r, half * 25 + it) * 16);
      const float4 w0 = *(const float4*)(wrow + k);
      const float4 w1 = *(const float4*)(wrow + k + 4);
      s0 = fmaf(bf2f((u16)h8[0]), w0.x, s0);
      s1 = fmaf(bf2f((u16)h8[1]), w0.y, s1);
      s0 = fmaf(bf2f((u16)h8[2]), w0.z, s0);
      s1 = fmaf(bf2f((u16)h8[3]), w0.w, s1);
      s0 = fmaf(bf2f((u16)h8[4]), w1.x, s0);
      s1 = fmaf(bf2f((u16)h8[5]), w1.y, s1);
      s0 = fmaf(bf2f((u16)h8[6]), w1.z, s0);
      s1 = fmaf(bf2f((u16)h8[7]), w1.w, s1);
    }
    float s = s0 + s1;
    s += __shfl_xor(s, 4);           // combine K-halves, preserve j
    s += be3[j];
    zval = s;
    if (half == 0) z_out[(size_t)(row0 + r) * 4 + j] = s;
  }
  // no barrier: L3 reads A (own rows), L4 writes B.

  // ---- L4: g1 = lrelu(z @ Wd1 + bd1) -> plane B ----
  {
    const int r = tid >> 3, q = tid & 7;
    float z[4];
#pragma unroll
    for (int jj = 0; jj < 4; ++jj) z[jj] = __shfl(zval, (lane & ~7) + jj);
#pragma unroll 2
    for (int u = 0; u < 13; ++u) {
      const int c4 = q * 13 + u;                 // 104 groups of 4 cols = 416
      ushort4 hh;
      u16* hw = (u16*)&hh;
      if (c4 < 100) {                            // cols < 400
        const float4 w0 = *(const float4*)(Wd1 + 0 * HREAL + c4 * 4);
        const float4 w1 = *(const float4*)(Wd1 + 1 * HREAL + c4 * 4);
        const float4 w2 = *(const float4*)(Wd1 + 2 * HREAL + c4 * 4);
        const float4 w3 = *(const float4*)(Wd1 + 3 * HREAL + c4 * 4);
        const float4 bb = *(const float4*)(bd1 + c4 * 4);
        const float ww[4][4] = {{w0.x, w1.x, w2.x, w3.x}, {w0.y, w1.y, w2.y, w3.y},
                                {w0.z, w1.z, w2.z, w3.z}, {w0.w, w1.w, w2.w, w3.w}};
        const float bbv[4] = {bb.x, bb.y, bb.z, bb.w};
#pragma unroll
        for (int w = 0; w < 4; ++w) {
          float v = fmaf(z[0], ww[w][0], fmaf(z[1], ww[w][1],
                    fmaf(z[2], ww[w][2], fmaf(z[3], ww[w][3], bbv[w]))));
          v = fmaxf(v, 0.1f * v);
          hw[w] = f2bf(v);
        }
      } else {
        hw[0] = hw[1] = hw[2] = hw[3] = 0;
      }
      *(ushort4*)(pb + r * PROW + rotu(r, c4 >> 1) * 16 + (c4 & 1) * 8) = hh;
    }
  }
  __syncthreads();

  // ---- L5: g2 = lrelu(g1(B) @ Wd2 + bd2) -> plane A ----
  for (int c = wid; c < 13; c += 4) {
    f32x4 acc[2][2] = {};
    gemm2<13>(pb, W5, 2 * c, l15, g, acc);
    epi2(acc, bd2, 2 * c, pa, l15, g);
  }
  __syncthreads();                 // B now free (red overlay), A holds g2

  // ---- L6: y = tanh(g2(A) @ Wd3 + bd3) + fused reductions ----
  // 7 chunks of 2 nb over 4 waves: w0:{0,4} w1:{1,5} w2:{2,6} w3:{3}
  {
    float pA[2][4] = {}, pB[2][4] = {}, pM[2][4] = {};
    for (int c = wid; c < 7; c += 4) {
      const int nb0 = 2 * c;
      f32x4 acc[2][2] = {};
      gemm2<13>(pa, W6, nb0, l15, g, acc);
#pragma unroll
      for (int mf = 0; mf < 2; ++mf) {
#pragma unroll
        for (int j = 0; j < 4; ++j) {
          const int grow = row0 + mf * 16 + g * 4 + j;
#pragma unroll
          for (int nf = 0; nf < 2; ++nf) {
            const int col = (nb0 + nf) * 16 + l15;
            const float v = acc[mf][nf][j] + bd3[col];
            const float e = __expf(2.f * v);
            const float y = 1.f - 2.f * __builtin_amdgcn_rcpf(e + 1.f);
            y_out[(size_t)grow * DDIM + col] = y;
            pA[mf][j] = fmaf(y, dvec[col], pA[mf][j]);
            pB[mf][j] = fmaf(y, y, pB[mf][j]);
            const float df = y - xin[(size_t)grow * DDIM + col];
            pM[mf][j] = fmaf(df, df, pM[mf][j]);
          }
        }
      }
    }
    float* red = (float*)pb;       // [32 rows][4 waves][4]
#pragma unroll
    for (int mf = 0; mf < 2; ++mf) {
#pragma unroll
      for (int j = 0; j < 4; ++j) {
        float a = pA[mf][j], b = pB[mf][j], m = pM[mf][j];
#pragma unroll
        for (int off = 1; off < 16; off <<= 1) {
          a += __shfl_xor(a, off);
          b += __shfl_xor(b, off);
          m += __shfl_xor(m, off);
        }
        if (l15 == 0) {
          const int lrow = mf * 16 + g * 4 + j;
          red[(lrow * 4 + wid) * 4 + 0] = a;
          red[(lrow * 4 + wid) * 4 + 1] = b;
          red[(lrow * 4 + wid) * 4 + 2] = m;
        }
      }
    }
  }
  __syncthreads();

  if (tid < 32) {
    const float Cn = Cptr[0];
    const float* red = (const float*)pb;
    float A = 0.f, B2 = 0.f, M = 0.f;
#pragma unroll
    for (int w = 0; w < 4; ++w) {
      A  += red[(tid * 4 + w) * 4 + 0];
      B2 += red[(tid * 4 + w) * 4 + 1];
      M  += red[(tid * 4 + w) * 4 + 2];
    }
    defen[row0 + tid] = A / (sqrtf(B2) * Cn + 1e-5f);
#pragma unroll
    for (int off = 1; off < 32; off <<= 1) M += __shfl_xor(M, off);
    if (tid == 0) msep[blockIdx.x] = M;
  }
}

// ---------------- top-k stage A: 64 blocks, per-block top-20 of 2048 ----------------
__global__ void k_topk_a(const float* __restrict__ defen, float* __restrict__ cand) {
  __shared__ float vals[2048];
  __shared__ float wv[4];
  __shared__ int wi[4];
  const int tid = threadIdx.x;
  const int base = blockIdx.x * 2048;
  for (int i = tid; i < 2048; i += 256) vals[i] = defen[base + i];
  __syncthreads();
  for (int it = 0; it < 20; ++it) {
    float mv = -1e30f; int mi = 1 << 30;
    for (int i = tid; i < 2048; i += 256) {
      float v = vals[i];
      if (v > mv) { mv = v; mi = i; }
    }
#pragma unroll
    for (int off = 1; off < 64; off <<= 1) {
      float ov = __shfl_xor(mv, off); int oi = __shfl_xor(mi, off);
      if (ov > mv || (ov == mv && oi < mi)) { mv = ov; mi = oi; }
    }
    if ((tid & 63) == 0) { wv[tid >> 6] = mv; wi[tid >> 6] = mi; }
    __syncthreads();
    if (tid == 0) {
      float bv = wv[0]; int bi = wi[0];
      for (int q = 1; q < 4; ++q)
        if (wv[q] > bv || (wv[q] == bv && wi[q] < bi)) { bv = wv[q]; bi = wi[q]; }
      cand[blockIdx.x * 20 + it] = bv;
      vals[bi] = -1e30f;
    }
    __syncthreads();
  }
}

// ---------------- top-k stage B: final top-20 of 1280 + R_loss ----------------
__global__ void k_topk_b(const float* __restrict__ cand, const float* __restrict__ msep,
                         float* __restrict__ rloss) {
  __shared__ float vals[1280];
  __shared__ float wv[4];
  __shared__ int wi[4];
  __shared__ float msum[4];
  const int tid = threadIdx.x;
  for (int i = tid; i < 1280; i += 256) vals[i] = cand[i];
  float ms = 0.f;
  for (int i = tid; i < 4096; i += 256) ms += msep[i];
#pragma unroll
  for (int off = 1; off < 64; off <<= 1) ms += __shfl_xor(ms, off);
  if ((tid & 63) == 0) msum[tid >> 6] = ms;
  __syncthreads();
  float sam = 0.f;
  for (int it = 0; it < 20; ++it) {
    float mv = -1e30f; int mi = 1 << 30;
    for (int i = tid; i < 1280; i += 256) {
      float v = vals[i];
      if (v > mv) { mv = v; mi = i; }
    }
#pragma unroll
    for (int off = 1; off < 64; off <<= 1) {
      float ov = __shfl_xor(mv, off); int oi = __shfl_xor(mi, off);
      if (ov > mv || (ov == mv && oi < mi)) { mv = ov; mi = oi; }
    }
    if ((tid & 63) == 0) { wv[tid >> 6] = mv; wi[tid >> 6] = mi; }
    __syncthreads();
    if (tid == 0) {
      float bv = wv[0]; int bi = wi[0];
      for (int q = 1; q < 4; ++q)
        if (wv[q] > bv || (wv[q] == bv && wi[q] < bi)) { bv = wv[q]; bi = wi[q]; }
      sam += bv;
      vals[bi] = -1e30f;
    }
    __syncthreads();
  }
  if (tid == 0) {
    float mse = (msum[0] + msum[1] + msum[2] + msum[3]) / 29360128.f;  // N*D
    rloss[0] = mse + 0.1f * sam;
  }
}

extern "C" void kernel_launch(void* const* d_in, const int* in_sizes, int n_in,
                              void* d_out, int out_size, void* d_ws, size_t ws_size,
                              hipStream_t stream) {
  const float* x    = (const float*)d_in[0];
  const float* dinp = (const float*)d_in[1];
  const float* We1  = (const float*)d_in[2];
  const float* be1  = (const float*)d_in[3];
  const float* We2  = (const float*)d_in[4];
  const float* be2  = (const float*)d_in[5];
  const float* We3  = (const float*)d_in[6];
  const float* be3  = (const float*)d_in[7];
  const float* Wd1  = (const float*)d_in[8];
  const float* bd1  = (const float*)d_in[9];
  const float* Wd2  = (const float*)d_in[10];
  const float* bd2  = (const float*)d_in[11];
  const float* Wd3  = (const float*)d_in[12];
  const float* bd3  = (const float*)d_in[13];

  float* y_out = (float*)d_out;
  float* z_out = y_out + (size_t)NROWS * DDIM;
  float* r_out = z_out + (size_t)NROWS * 4;

  char* ws = (char*)d_ws;
  u16* W1 = (u16*)(ws + OFF_W1);
  u16* W2 = (u16*)(ws + OFF_W2);
  u16* W5 = (u16*)(ws + OFF_W5);
  u16* W6 = (u16*)(ws + OFF_W6);
  float* Cf    = (float*)(ws + OFF_C);
  float* msep  = (float*)(ws + OFF_MSEP);
  float* defen = (float*)(ws + OFF_DEFEN);
  float* cand  = (float*)(ws + OFF_CAND);
  float* We3T  = (float*)(ws + OFF_WE3T);

  (void)hipFuncSetAttribute((const void*)k_main, hipFuncAttributeMaxDynamicSharedMemorySize, LDS_TOTAL);

  k_prep<<<dim3(256), dim3(256), 0, stream>>>(We1, We2, Wd2, Wd3, We3, dinp,
                                              W1, W2, W5, W6, We3T, Cf);
  k_main<<<dim3(4096), dim3(256), LDS_TOTAL, stream>>>(x, dinp, be1, be2, be3, bd1, bd2, bd3,
                                                       We3T, Wd1, W1, W2, W5, W6,
                                                       Cf, y_out, z_out, defen, msep);
  k_topk_a<<<dim3(64), dim3(256), 0, stream>>>(defen, cand);
  k_topk_b<<<dim3(1), dim3(256), 0, stream>>>(cand, msep, r_out);
}